// Round 1
// baseline (411.284 us; speedup 1.0000x reference)
//
#include <hip/hip_runtime.h>

#define DM    2048
#define NH    16
#define HD    128
#define TSEQ  2048
#define BATCH 2
#define MROWS (BATCH * TSEQ)   // 4096

typedef __bf16 bf16_t;
typedef __bf16 bf16x8 __attribute__((ext_vector_type(8)));
typedef float  f32x4  __attribute__((ext_vector_type(4)));
typedef unsigned short u16x8 __attribute__((ext_vector_type(8)));

static __device__ __forceinline__ unsigned short f2bf_bits(float f) {
  unsigned u = __builtin_bit_cast(unsigned, f);
  u += 0x7fffu + ((u >> 16) & 1u);            // round-to-nearest-even
  return (unsigned short)(u >> 16);
}
static __device__ __forceinline__ bf16_t f2bf(float f) {
  unsigned short h = f2bf_bits(f);
  return __builtin_bit_cast(bf16_t, h);
}

static __device__ __forceinline__ void gll16(const void* g, void* lds) {
  __builtin_amdgcn_global_load_lds(
      (const __attribute__((address_space(1))) unsigned int*)g,
      (__attribute__((address_space(3))) unsigned int*)lds, 16, 0, 0);
}

static __device__ __forceinline__ float fast_exp2(float x) {
#if __has_builtin(__builtin_amdgcn_exp2f)
  return __builtin_amdgcn_exp2f(x);
#else
  return exp2f(x);
#endif
}
static __device__ __forceinline__ float fast_rcp(float x) {
#if __has_builtin(__builtin_amdgcn_rcpf)
  return __builtin_amdgcn_rcpf(x);
#else
  return 1.0f / x;
#endif
}

// ---------------- fp32 -> bf16 convert (vectorized, G13) ----------------
__global__ void cvt_bf16(const float* __restrict__ s, bf16_t* __restrict__ d, int n8) {
  int i = blockIdx.x * blockDim.x + threadIdx.x;
  if (i >= n8) return;
  const float4* sp = reinterpret_cast<const float4*>(s);
  float4 a = sp[2 * i], b = sp[2 * i + 1];
  u16x8 o;
  o[0] = f2bf_bits(a.x); o[1] = f2bf_bits(a.y); o[2] = f2bf_bits(a.z); o[3] = f2bf_bits(a.w);
  o[4] = f2bf_bits(b.x); o[5] = f2bf_bits(b.y); o[6] = f2bf_bits(b.z); o[7] = f2bf_bits(b.w);
  reinterpret_cast<u16x8*>(d)[i] = o;
}

// ---------------- GEMM: C[M,N] = A[M,K] * B[N,K]^T  (m97 structure) ----------------
// M=4096, N=K=2048 hardcoded. 128x128 tile, BK=32, 4 waves in 2x2 of 64x64.
static __device__ __forceinline__ void store_c(float* p, float v)  { *p = v; }
static __device__ __forceinline__ void store_c(bf16_t* p, float v) { *p = f2bf(v); }

template <typename OutT>
__global__ __launch_bounds__(256, 2) void gemm_bt(
    const bf16_t* __restrict__ A, const bf16_t* __restrict__ B, OutT* __restrict__ C) {
  __shared__ bf16_t As[128 * 32];
  __shared__ bf16_t Bs[128 * 32];
  const int tid = threadIdx.x;
  const int l = tid & 63, w = tid >> 6;
  const int wr = w >> 1, wc = w & 1;
  const int m0 = blockIdx.y * 128, n0 = blockIdx.x * 128;
  const int srow  = (l >> 2);        // staging: row within 16-row chunk
  const int skoff = (l & 3) * 8;     // staging: k offset (8 bf16 = 16B)

  f32x4 acc[4][4] = {};

  for (int k0 = 0; k0 < DM; k0 += 32) {
#pragma unroll
    for (int c = 0; c < 2; ++c) {
      const int chunk = w * 2 + c;
      const int row = chunk * 16 + srow;
      gll16(A + (size_t)(m0 + row) * DM + k0 + skoff, (char*)As + chunk * 1024);
      gll16(B + (size_t)(n0 + row) * DM + k0 + skoff, (char*)Bs + chunk * 1024);
    }
    __syncthreads();
    bf16x8 af[4], bfr[4];
    const bf16x8* Ap = reinterpret_cast<const bf16x8*>(As);
    const bf16x8* Bp = reinterpret_cast<const bf16x8*>(Bs);
#pragma unroll
    for (int m = 0; m < 4; ++m) af[m]  = Ap[(wr * 64 + m * 16 + (l & 15)) * 4 + (l >> 4)];
#pragma unroll
    for (int n = 0; n < 4; ++n) bfr[n] = Bp[(wc * 64 + n * 16 + (l & 15)) * 4 + (l >> 4)];
#pragma unroll
    for (int m = 0; m < 4; ++m)
#pragma unroll
      for (int n = 0; n < 4; ++n)
        acc[m][n] = __builtin_amdgcn_mfma_f32_16x16x32_bf16(af[m], bfr[n], acc[m][n], 0, 0, 0);
    __syncthreads();
  }

#pragma unroll
  for (int m = 0; m < 4; ++m) {
    const int row = m0 + wr * 64 + m * 16 + ((l >> 4) << 2);
#pragma unroll
    for (int n = 0; n < 4; ++n) {
      const int col = n0 + wc * 64 + n * 16 + (l & 15);
#pragma unroll
      for (int r = 0; r < 4; ++r)
        store_c(C + (size_t)(row + r) * DM + col, acc[m][n][r]);
    }
  }
}

// ---------------- causal flash attention ----------------
// grid: (T/64, B*H). Block: 256 thr = 4 waves, each wave 16 q-rows.
// Q/K/V/O layout: [B, T, H*HD] (head h = cols h*HD .. h*HD+127).
__global__ __launch_bounds__(256, 2) void flash_attn(
    const bf16_t* __restrict__ Q, const bf16_t* __restrict__ Kx,
    const bf16_t* __restrict__ V, bf16_t* __restrict__ O) {
  __shared__ bf16_t Ks[64 * 128];      // K tile, rows=kv, 256B rows, XOR-swizzled content
  __shared__ bf16_t VTs[128 * 64];     // V^T tile, rows=d, 128B rows, XOR-swizzled
  __shared__ bf16_t Ps[4][16 * 64];    // per-wave P, 128B rows, XOR-swizzled

  const int tid = threadIdx.x;
  const int l = tid & 63, w = tid >> 6;
  const int qb = blockIdx.x, bh = blockIdx.y;
  const int b = bh >> 4, h = bh & 15;
  const size_t base = ((size_t)b * TSEQ) * DM + (size_t)h * HD;
  const int qbase = qb * 64;

  // Q fragments in registers (A-layout: row=l&15, k=(l>>4)*8+j)
  bf16x8 qf[4];
  {
    const int qrow = qbase + w * 16 + (l & 15);
    const bf16_t* qp = Q + base + (size_t)qrow * DM + (l >> 4) * 8;
#pragma unroll
    for (int ds = 0; ds < 4; ++ds)
      qf[ds] = *reinterpret_cast<const bf16x8*>(qp + ds * 32);
  }

  f32x4 acc[8] = {};
  float mrow[4] = {-1e30f, -1e30f, -1e30f, -1e30f};
  float lrow[4] = {0.f, 0.f, 0.f, 0.f};
  const float cc = 0.12752775f;  // (1/sqrt(128)) * log2(e)

  for (int t = 0; t <= qb; ++t) {
    // stage K: 16 chunks of 1024B (4 rows each); swizzle via pre-swizzled global source
#pragma unroll
    for (int c = 0; c < 4; ++c) {
      const int chunk = w * 4 + c;
      const int krow = chunk * 4 + (l >> 4);
      const int u = l & 15;
      const int ug = (u & 8) | ((u ^ krow) & 7);
      gll16(Kx + base + (size_t)(t * 64 + krow) * DM + ug * 8, (char*)Ks + chunk * 1024);
    }
    // stage V transposed: lane = kv row, wave = d-quarter; swizzled ds writes (conflict-free)
    {
      const bf16_t* vp = V + base + (size_t)(t * 64 + l) * DM + w * 32;
      bf16x8 vv[4];
#pragma unroll
      for (int i = 0; i < 4; ++i)
        vv[i] = *reinterpret_cast<const bf16x8*>(vp + i * 8);
#pragma unroll
      for (int i = 0; i < 4; ++i)
#pragma unroll
        for (int j = 0; j < 8; ++j) {
          const int d = w * 32 + i * 8 + j;
          const int byteoff = (d << 7) + ((l << 1) ^ (j << 4));
          *(bf16_t*)((char*)VTs + byteoff) = vv[i][j];
        }
    }
    __syncthreads();

    // S = Q K^T  (16 q-rows x 64 kv-cols per wave)
    f32x4 s[4] = {};
#pragma unroll
    for (int ct = 0; ct < 4; ++ct) {
      const int krow = ct * 16 + (l & 15);
#pragma unroll
      for (int ds = 0; ds < 4; ++ds) {
        const int u = ds * 4 + (l >> 4);
        const int uswz = (u & 8) | ((u ^ krow) & 7);
        const bf16x8 kf = *reinterpret_cast<const bf16x8*>((char*)Ks + krow * 256 + uswz * 16);
        s[ct] = __builtin_amdgcn_mfma_f32_16x16x32_bf16(qf[ds], kf, s[ct], 0, 0, 0);
      }
    }

    float sv[4][4];
#pragma unroll
    for (int ct = 0; ct < 4; ++ct)
#pragma unroll
      for (int r = 0; r < 4; ++r)
        sv[ct][r] = s[ct][r] * cc;

    if (t == qb) {  // causal mask, diagonal tile only
      const int rowl = w * 16 + ((l >> 4) << 2);
#pragma unroll
      for (int ct = 0; ct < 4; ++ct) {
        const int coll = ct * 16 + (l & 15);
#pragma unroll
        for (int r = 0; r < 4; ++r)
          if (coll > rowl + r) sv[ct][r] = -1e30f;
      }
    }

    // wave-parallel online softmax (row = 16-lane group; shfl_xor reduce)
    float mt[4];
#pragma unroll
    for (int r = 0; r < 4; ++r)
      mt[r] = fmaxf(fmaxf(sv[0][r], sv[1][r]), fmaxf(sv[2][r], sv[3][r]));
#pragma unroll
    for (int r = 0; r < 4; ++r) {
      mt[r] = fmaxf(mt[r], __shfl_xor(mt[r], 1, 64));
      mt[r] = fmaxf(mt[r], __shfl_xor(mt[r], 2, 64));
      mt[r] = fmaxf(mt[r], __shfl_xor(mt[r], 4, 64));
      mt[r] = fmaxf(mt[r], __shfl_xor(mt[r], 8, 64));
    }
    float scl[4], rs[4];
#pragma unroll
    for (int r = 0; r < 4; ++r) {
      const float mn = fmaxf(mrow[r], mt[r]);
      scl[r] = fast_exp2(mrow[r] - mn);
      mrow[r] = mn;
      rs[r] = 0.f;
    }
#pragma unroll
    for (int ct = 0; ct < 4; ++ct)
#pragma unroll
      for (int r = 0; r < 4; ++r) {
        const float p = fast_exp2(sv[ct][r] - mrow[r]);
        sv[ct][r] = p;
        rs[r] += p;
      }
#pragma unroll
    for (int r = 0; r < 4; ++r) {
      rs[r] += __shfl_xor(rs[r], 1, 64);
      rs[r] += __shfl_xor(rs[r], 2, 64);
      rs[r] += __shfl_xor(rs[r], 4, 64);
      rs[r] += __shfl_xor(rs[r], 8, 64);
      lrow[r] = lrow[r] * scl[r] + rs[r];
    }
#pragma unroll
    for (int n = 0; n < 8; ++n)
#pragma unroll
      for (int r = 0; r < 4; ++r)
        acc[n][r] *= scl[r];

    // P (D-layout) -> wave-private LDS (swizzled), to re-read in A-layout
    bf16_t* Pw = Ps[w];
#pragma unroll
    for (int ct = 0; ct < 4; ++ct)
#pragma unroll
      for (int r = 0; r < 4; ++r) {
        const int prow = ((l >> 4) << 2) + r;
        const int pcol = ct * 16 + (l & 15);
        const int byteoff = (prow << 7) + ((pcol << 1) ^ ((prow & 7) << 4));
        *(bf16_t*)((char*)Pw + byteoff) = f2bf(sv[ct][r]);
      }

    // O += P * V
#pragma unroll
    for (int ks = 0; ks < 2; ++ks) {
      const int prow = l & 15;
      const int pu = (ks * 4 + (l >> 4)) ^ (prow & 7);
      const bf16x8 pf = *reinterpret_cast<const bf16x8*>((char*)Pw + prow * 128 + pu * 16);
#pragma unroll
      for (int n = 0; n < 8; ++n) {
        const int vrow = n * 16 + (l & 15);
        const int vu = (ks * 4 + (l >> 4)) ^ (vrow & 7);
        const bf16x8 vf = *reinterpret_cast<const bf16x8*>((char*)VTs + vrow * 128 + vu * 16);
        acc[n] = __builtin_amdgcn_mfma_f32_16x16x32_bf16(pf, vf, acc[n], 0, 0, 0);
      }
    }
    __syncthreads();
  }

  // epilogue: normalize and store bf16
#pragma unroll
  for (int r = 0; r < 4; ++r) {
    const float rl = fast_rcp(lrow[r]);
    const int row = qbase + w * 16 + ((l >> 4) << 2) + r;
    bf16_t* op = O + base + (size_t)row * DM + (l & 15);
#pragma unroll
    for (int n = 0; n < 8; ++n)
      op[n * 16] = f2bf(acc[n][r] * rl);
  }
}

// ---------------- launch ----------------
extern "C" void kernel_launch(void* const* d_in, const int* in_sizes, int n_in,
                              void* d_out, int out_size, void* d_ws, size_t ws_size,
                              hipStream_t stream) {
  (void)in_sizes; (void)n_in; (void)out_size; (void)ws_size;
  const float* x  = (const float*)d_in[0];
  const float* wq = (const float*)d_in[1];
  const float* wk = (const float*)d_in[2];
  const float* wv = (const float*)d_in[3];
  const float* wo = (const float*)d_in[4];
  float* out = (float*)d_out;

  const size_t nx = (size_t)MROWS * DM;  // 8388608
  const size_t nw = (size_t)DM * DM;     // 4194304
  bf16_t* xb  = (bf16_t*)d_ws;
  bf16_t* wqb = xb + nx;
  bf16_t* wkb = wqb + nw;
  bf16_t* wvb = wkb + nw;
  bf16_t* wob = wvb + nw;
  bf16_t* Qb  = wob + nw;
  bf16_t* Kb  = Qb + nx;
  bf16_t* Vb  = Kb + nx;
  bf16_t* Ab  = Vb + nx;

  cvt_bf16<<<(int)(nx / 8 / 256), 256, 0, stream>>>(x, xb, (int)(nx / 8));
  cvt_bf16<<<(int)(nw / 8 / 256), 256, 0, stream>>>(wq, wqb, (int)(nw / 8));
  cvt_bf16<<<(int)(nw / 8 / 256), 256, 0, stream>>>(wk, wkb, (int)(nw / 8));
  cvt_bf16<<<(int)(nw / 8 / 256), 256, 0, stream>>>(wv, wvb, (int)(nw / 8));
  cvt_bf16<<<(int)(nw / 8 / 256), 256, 0, stream>>>(wo, wob, (int)(nw / 8));

  dim3 gg(DM / 128, MROWS / 128);  // (16, 32)
  gemm_bt<bf16_t><<<gg, 256, 0, stream>>>(xb, wqb, Qb);
  gemm_bt<bf16_t><<<gg, 256, 0, stream>>>(xb, wkb, Kb);
  gemm_bt<bf16_t><<<gg, 256, 0, stream>>>(xb, wvb, Vb);

  flash_attn<<<dim3(TSEQ / 64, BATCH * NH), 256, 0, stream>>>(Qb, Kb, Vb, Ab);

  gemm_bt<float><<<gg, 256, 0, stream>>>(Ab, wob, out);
}

// Round 2
// 349.370 us; speedup vs baseline: 1.1772x; 1.1772x over previous
//
#include <hip/hip_runtime.h>

#define DM    2048
#define NH    16
#define HD    128
#define TSEQ  2048
#define BATCH 2
#define MROWS (BATCH * TSEQ)   // 4096

typedef __bf16 bf16_t;
typedef __bf16 bf16x8 __attribute__((ext_vector_type(8)));
typedef __bf16 bf16x4 __attribute__((ext_vector_type(4)));
typedef float  f32x4  __attribute__((ext_vector_type(4)));
typedef unsigned short u16x8 __attribute__((ext_vector_type(8)));

static __device__ __forceinline__ unsigned short f2bf_bits(float f) {
  unsigned u = __builtin_bit_cast(unsigned, f);
  u += 0x7fffu + ((u >> 16) & 1u);            // round-to-nearest-even
  return (unsigned short)(u >> 16);
}
static __device__ __forceinline__ bf16_t f2bf(float f) {
  unsigned short h = f2bf_bits(f);
  return __builtin_bit_cast(bf16_t, h);
}

static __device__ __forceinline__ void gll16(const void* g, void* lds) {
  __builtin_amdgcn_global_load_lds(
      (const __attribute__((address_space(1))) unsigned int*)g,
      (__attribute__((address_space(3))) unsigned int*)lds, 16, 0, 0);
}

typedef const __attribute__((address_space(3))) bf16_t* lds_cptr;
static __device__ __forceinline__ bf16x4 tr0(const bf16_t* p) {
  bf16x4 d;
  asm volatile("ds_read_b64_tr_b16 %0, %1" : "=v"(d) : "v"((lds_cptr)p));
  return d;
}
static __device__ __forceinline__ bf16x4 tr128(const bf16_t* p) {
  bf16x4 d;
  asm volatile("ds_read_b64_tr_b16 %0, %1 offset:128" : "=v"(d) : "v"((lds_cptr)p));
  return d;
}

static __device__ __forceinline__ float fast_exp2(float x) {
#if __has_builtin(__builtin_amdgcn_exp2f)
  return __builtin_amdgcn_exp2f(x);
#else
  return exp2f(x);
#endif
}
static __device__ __forceinline__ float fast_rcp(float x) {
#if __has_builtin(__builtin_amdgcn_rcpf)
  return __builtin_amdgcn_rcpf(x);
#else
  return 1.0f / x;
#endif
}

// ---------------- fp32 -> bf16 convert (vectorized, G13) ----------------
__global__ void cvt_bf16(const float* __restrict__ s, bf16_t* __restrict__ d, int n8) {
  int i = blockIdx.x * blockDim.x + threadIdx.x;
  if (i >= n8) return;
  const float4* sp = reinterpret_cast<const float4*>(s);
  float4 a = sp[2 * i], b = sp[2 * i + 1];
  u16x8 o;
  o[0] = f2bf_bits(a.x); o[1] = f2bf_bits(a.y); o[2] = f2bf_bits(a.z); o[3] = f2bf_bits(a.w);
  o[4] = f2bf_bits(b.x); o[5] = f2bf_bits(b.y); o[6] = f2bf_bits(b.z); o[7] = f2bf_bits(b.w);
  reinterpret_cast<u16x8*>(d)[i] = o;
}

// ---------------- GEMM: C[M,N] = A[M,K] * B[N,K]^T  (m97 structure) ----------------
static __device__ __forceinline__ void store_c(float* p, float v)  { *p = v; }
static __device__ __forceinline__ void store_c(bf16_t* p, float v) { *p = f2bf(v); }

template <typename OutT>
__global__ __launch_bounds__(256, 2) void gemm_bt(
    const bf16_t* __restrict__ A, const bf16_t* __restrict__ B, OutT* __restrict__ C) {
  __shared__ bf16_t As[128 * 32];
  __shared__ bf16_t Bs[128 * 32];
  const int tid = threadIdx.x;
  const int l = tid & 63, w = tid >> 6;
  const int wr = w >> 1, wc = w & 1;
  const int m0 = blockIdx.y * 128, n0 = blockIdx.x * 128;
  const int srow  = (l >> 2);
  const int skoff = (l & 3) * 8;

  f32x4 acc[4][4] = {};

  for (int k0 = 0; k0 < DM; k0 += 32) {
#pragma unroll
    for (int c = 0; c < 2; ++c) {
      const int chunk = w * 2 + c;
      const int row = chunk * 16 + srow;
      gll16(A + (size_t)(m0 + row) * DM + k0 + skoff, (char*)As + chunk * 1024);
      gll16(B + (size_t)(n0 + row) * DM + k0 + skoff, (char*)Bs + chunk * 1024);
    }
    __syncthreads();
    bf16x8 af[4], bfr[4];
    const bf16x8* Ap = reinterpret_cast<const bf16x8*>(As);
    const bf16x8* Bp = reinterpret_cast<const bf16x8*>(Bs);
#pragma unroll
    for (int m = 0; m < 4; ++m) af[m]  = Ap[(wr * 64 + m * 16 + (l & 15)) * 4 + (l >> 4)];
#pragma unroll
    for (int n = 0; n < 4; ++n) bfr[n] = Bp[(wc * 64 + n * 16 + (l & 15)) * 4 + (l >> 4)];
#pragma unroll
    for (int m = 0; m < 4; ++m)
#pragma unroll
      for (int n = 0; n < 4; ++n)
        acc[m][n] = __builtin_amdgcn_mfma_f32_16x16x32_bf16(af[m], bfr[n], acc[m][n], 0, 0, 0);
    __syncthreads();
  }

#pragma unroll
  for (int m = 0; m < 4; ++m) {
    const int row = m0 + wr * 64 + m * 16 + ((l >> 4) << 2);
#pragma unroll
    for (int n = 0; n < 4; ++n) {
      const int col = n0 + wc * 64 + n * 16 + (l & 15);
#pragma unroll
      for (int r = 0; r < 4; ++r)
        store_c(C + (size_t)(row + r) * DM + col, acc[m][n][r]);
    }
  }
}

// ---------------- causal flash attention v2 ----------------
// grid: (T/128, B*H). Block: 512 thr = 8 waves, each wave 16 q-rows.
// 2-phase pipeline: STAGE(t+1) || COMPUTE(t); one barrier per iter.
// K LDS: [64 kv][128 d] rows 256B, XOR-swizzled content (via pre-swz global src).
// V LDS: [8 db][16 kb][4 k][16 d] subtiles; consumed via ds_read_b64_tr_b16.
__global__ __launch_bounds__(512, 4) void flash_attn(
    const bf16_t* __restrict__ Q, const bf16_t* __restrict__ Kx,
    const bf16_t* __restrict__ V, bf16_t* __restrict__ O) {
  __shared__ bf16_t Ks[2][64 * 128];
  __shared__ bf16_t Vs[2][64 * 128];
  __shared__ bf16_t Ps[8][16 * 64];

  const int tid = threadIdx.x;
  const int l = tid & 63, w = tid >> 6;
  const int qb = (int)gridDim.x - 1 - (int)blockIdx.x;  // long blocks first
  const int bh = blockIdx.y;
  const int b = bh >> 4, h = bh & 15;
  const size_t base = ((size_t)b * TSEQ) * DM + (size_t)h * HD;
  const int qbase = qb * 128;
  const int wrow0 = qbase + w * 16;
  const int nt = 2 * qb + 2;

  // Q fragments (A-layout: row=l&15, k=(l>>4)*8+j)
  bf16x8 qf[4];
  {
    const bf16_t* qp = Q + base + (size_t)(wrow0 + (l & 15)) * DM + (l >> 4) * 8;
#pragma unroll
    for (int ds = 0; ds < 4; ++ds)
      qf[ds] = *reinterpret_cast<const bf16x8*>(qp + ds * 32);
  }

  f32x4 acc[8] = {};
  float mrow[4] = {-1e30f, -1e30f, -1e30f, -1e30f};
  float lrow[4] = {0.f, 0.f, 0.f, 0.f};
  const float cc = 0.12752775f;  // (1/sqrt(128)) * log2(e)

  // ---- staging: per wave 2 K-chunks + 2 V-chunks of 1024B ----
  auto STAGE = [&](int t, int buf) {
#pragma unroll
    for (int c = 0; c < 2; ++c) {
      const int chunk = w * 2 + c;                   // 0..15
      const int krow = chunk * 4 + (l >> 4);
      const int u = l & 15;
      const int ug = (u & 8) | ((u ^ krow) & 7);
      gll16(Kx + base + (size_t)(t * 64 + krow) * DM + ug * 8,
            (char*)Ks[buf] + chunk * 1024);
    }
#pragma unroll
    for (int c = 0; c < 2; ++c) {
      const int ci = w * 2 + c;                      // 0..15
      const int db = ci >> 1, half = ci & 1;
      const int kb = half * 8 + (l >> 3);
      const int r = (l >> 1) & 3;
      const int k = kb * 4 + r;
      gll16(V + base + (size_t)(t * 64 + k) * DM + db * 16 + (l & 1) * 8,
            (char*)Vs[buf] + ci * 1024);
    }
  };

  STAGE(0, 0);
  __syncthreads();
  int cur = 0;

  for (int t = 0; t < nt; ++t) {
    if (t + 1 < nt) STAGE(t + 1, cur ^ 1);

    const bool active = (t * 64 <= wrow0 + 15);
    if (active) {
      // ---- S = Q K^T ----
      f32x4 s[4] = {};
      const char* Kb_ = (const char*)Ks[cur];
#pragma unroll
      for (int ct = 0; ct < 4; ++ct) {
        const int krow = ct * 16 + (l & 15);
#pragma unroll
        for (int ds = 0; ds < 4; ++ds) {
          const int u = ds * 4 + (l >> 4);
          const int uswz = (u & 8) | ((u ^ krow) & 7);
          const bf16x8 kf = *reinterpret_cast<const bf16x8*>(Kb_ + krow * 256 + uswz * 16);
          s[ct] = __builtin_amdgcn_mfma_f32_16x16x32_bf16(qf[ds], kf, s[ct], 0, 0, 0);
        }
      }

      float sv[4][4];
#pragma unroll
      for (int ct = 0; ct < 4; ++ct)
#pragma unroll
        for (int r = 0; r < 4; ++r)
          sv[ct][r] = s[ct][r] * cc;

      if (t * 64 + 63 > wrow0) {  // tile touches the diagonal for this wave
        const int rowg = wrow0 + ((l >> 4) << 2);
#pragma unroll
        for (int ct = 0; ct < 4; ++ct) {
          const int colg = t * 64 + ct * 16 + (l & 15);
#pragma unroll
          for (int r = 0; r < 4; ++r)
            if (colg > rowg + r) sv[ct][r] = -3.0e38f;
        }
      }

      // ---- wave-parallel online softmax (row = 16-lane group) ----
      float mt[4];
#pragma unroll
      for (int r = 0; r < 4; ++r)
        mt[r] = fmaxf(fmaxf(sv[0][r], sv[1][r]), fmaxf(sv[2][r], sv[3][r]));
#pragma unroll
      for (int r = 0; r < 4; ++r) {
        mt[r] = fmaxf(mt[r], __shfl_xor(mt[r], 1, 64));
        mt[r] = fmaxf(mt[r], __shfl_xor(mt[r], 2, 64));
        mt[r] = fmaxf(mt[r], __shfl_xor(mt[r], 4, 64));
        mt[r] = fmaxf(mt[r], __shfl_xor(mt[r], 8, 64));
      }
      float scl[4], rs[4];
#pragma unroll
      for (int r = 0; r < 4; ++r) {
        const float mn = fmaxf(mrow[r], mt[r]);
        scl[r] = fast_exp2(mrow[r] - mn);
        mrow[r] = mn;
        rs[r] = 0.f;
      }
#pragma unroll
      for (int ct = 0; ct < 4; ++ct)
#pragma unroll
        for (int r = 0; r < 4; ++r) {
          const float p = fast_exp2(sv[ct][r] - mrow[r]);
          sv[ct][r] = p;
          rs[r] += p;
        }
#pragma unroll
      for (int r = 0; r < 4; ++r) {
        rs[r] += __shfl_xor(rs[r], 1, 64);
        rs[r] += __shfl_xor(rs[r], 2, 64);
        rs[r] += __shfl_xor(rs[r], 4, 64);
        rs[r] += __shfl_xor(rs[r], 8, 64);
        lrow[r] = lrow[r] * scl[r] + rs[r];
      }
#pragma unroll
      for (int n = 0; n < 8; ++n)
#pragma unroll
        for (int r = 0; r < 4; ++r)
          acc[n][r] *= scl[r];

      // ---- P (D-layout) -> wave-private swizzled LDS ----
      bf16_t* Pw = Ps[w];
#pragma unroll
      for (int ct = 0; ct < 4; ++ct)
#pragma unroll
        for (int r = 0; r < 4; ++r) {
          const int prow = ((l >> 4) << 2) + r;
          const int pcol = ct * 16 + (l & 15);
          const int byteoff = (prow << 7) + ((pcol << 1) ^ ((prow & 7) << 4));
          *(bf16_t*)((char*)Pw + byteoff) = f2bf(sv[ct][r]);
        }

      // ---- O += P * V (V via hw transpose reads) ----
      const char* Vb_ = (const char*)Vs[cur];
#pragma unroll
      for (int ks = 0; ks < 2; ++ks) {
        const int prow = l & 15;
        const int pu = (ks * 4 + (l >> 4)) ^ (prow & 7);
        const bf16x8 pf = *reinterpret_cast<const bf16x8*>((const char*)Pw + prow * 128 + pu * 16);
        const char* vb = Vb_ + (ks * 8 + 2 * (l >> 4)) * 128 + (l & 15) * 8;
#pragma unroll
        for (int half = 0; half < 2; ++half) {
          bf16x4 ta[8];
#pragma unroll
          for (int n = 0; n < 4; ++n) {
            const bf16_t* vp = (const bf16_t*)(vb + (half * 4 + n) * 2048);
            ta[2 * n]     = tr0(vp);
            ta[2 * n + 1] = tr128(vp);
          }
          asm volatile("s_waitcnt lgkmcnt(0)" ::: "memory");
          __builtin_amdgcn_sched_barrier(0);
#pragma unroll
          for (int n = 0; n < 4; ++n) {
            bf16x8 vf;
#pragma unroll
            for (int j = 0; j < 4; ++j) { vf[j] = ta[2 * n][j]; vf[4 + j] = ta[2 * n + 1][j]; }
            acc[half * 4 + n] =
                __builtin_amdgcn_mfma_f32_16x16x32_bf16(pf, vf, acc[half * 4 + n], 0, 0, 0);
          }
        }
      }
    }
    __syncthreads();
    cur ^= 1;
  }

  // ---- epilogue: normalize and store bf16 ----
#pragma unroll
  for (int r = 0; r < 4; ++r) {
    const float rl = fast_rcp(lrow[r]);
    const int row = wrow0 + ((l >> 4) << 2) + r;
    bf16_t* op = O + base + (size_t)row * DM + (l & 15);
#pragma unroll
    for (int n = 0; n < 8; ++n)
      op[n * 16] = f2bf(acc[n][r] * rl);
  }
}

// ---------------- launch ----------------
extern "C" void kernel_launch(void* const* d_in, const int* in_sizes, int n_in,
                              void* d_out, int out_size, void* d_ws, size_t ws_size,
                              hipStream_t stream) {
  (void)in_sizes; (void)n_in; (void)out_size; (void)ws_size;
  const float* x  = (const float*)d_in[0];
  const float* wq = (const float*)d_in[1];
  const float* wk = (const float*)d_in[2];
  const float* wv = (const float*)d_in[3];
  const float* wo = (const float*)d_in[4];
  float* out = (float*)d_out;

  const size_t nx = (size_t)MROWS * DM;  // 8388608
  const size_t nw = (size_t)DM * DM;     // 4194304
  bf16_t* xb  = (bf16_t*)d_ws;
  bf16_t* wqb = xb + nx;
  bf16_t* wkb = wqb + nw;
  bf16_t* wvb = wkb + nw;
  bf16_t* wob = wvb + nw;
  bf16_t* Qb  = wob + nw;
  bf16_t* Kb  = Qb + nx;
  bf16_t* Vb  = Kb + nx;
  bf16_t* Ab  = Vb + nx;

  cvt_bf16<<<(int)(nx / 8 / 256), 256, 0, stream>>>(x, xb, (int)(nx / 8));
  cvt_bf16<<<(int)(nw / 8 / 256), 256, 0, stream>>>(wq, wqb, (int)(nw / 8));
  cvt_bf16<<<(int)(nw / 8 / 256), 256, 0, stream>>>(wk, wkb, (int)(nw / 8));
  cvt_bf16<<<(int)(nw / 8 / 256), 256, 0, stream>>>(wv, wvb, (int)(nw / 8));
  cvt_bf16<<<(int)(nw / 8 / 256), 256, 0, stream>>>(wo, wob, (int)(nw / 8));

  dim3 gg(DM / 128, MROWS / 128);  // (16, 32)
  gemm_bt<bf16_t><<<gg, 256, 0, stream>>>(xb, wqb, Qb);
  gemm_bt<bf16_t><<<gg, 256, 0, stream>>>(xb, wkb, Kb);
  gemm_bt<bf16_t><<<gg, 256, 0, stream>>>(xb, wvb, Vb);

  flash_attn<<<dim3(TSEQ / 128, BATCH * NH), 512, 0, stream>>>(Qb, Kb, Vb, Ab);

  gemm_bt<float><<<gg, 256, 0, stream>>>(Ab, wob, out);
}

// Round 3
// 344.530 us; speedup vs baseline: 1.1938x; 1.0140x over previous
//
#include <hip/hip_runtime.h>

#define DM    2048
#define NH    16
#define HD    128
#define TSEQ  2048
#define BATCH 2
#define MROWS (BATCH * TSEQ)   // 4096

typedef __bf16 bf16_t;
typedef __bf16 bf16x8 __attribute__((ext_vector_type(8)));
typedef __bf16 bf16x4 __attribute__((ext_vector_type(4)));
typedef float  f32x4  __attribute__((ext_vector_type(4)));
typedef unsigned short u16x8 __attribute__((ext_vector_type(8)));

static __device__ __forceinline__ unsigned short f2bf_bits(float f) {
  unsigned u = __builtin_bit_cast(unsigned, f);
  u += 0x7fffu + ((u >> 16) & 1u);            // round-to-nearest-even
  return (unsigned short)(u >> 16);
}
static __device__ __forceinline__ bf16_t f2bf(float f) {
  unsigned short h = f2bf_bits(f);
  return __builtin_bit_cast(bf16_t, h);
}

static __device__ __forceinline__ void gll16(const void* g, void* lds) {
  __builtin_amdgcn_global_load_lds(
      (const __attribute__((address_space(1))) unsigned int*)g,
      (__attribute__((address_space(3))) unsigned int*)lds, 16, 0, 0);
}

static __device__ __forceinline__ float fast_exp2(float x) {
#if __has_builtin(__builtin_amdgcn_exp2f)
  return __builtin_amdgcn_exp2f(x);
#else
  return exp2f(x);
#endif
}
static __device__ __forceinline__ float fast_rcp(float x) {
#if __has_builtin(__builtin_amdgcn_rcpf)
  return __builtin_amdgcn_rcpf(x);
#else
  return 1.0f / x;
#endif
}

// ---------------- fp32 -> bf16 convert (vectorized, G13) ----------------
__global__ void cvt_bf16(const float* __restrict__ s, bf16_t* __restrict__ d, int n8) {
  int i = blockIdx.x * blockDim.x + threadIdx.x;
  if (i >= n8) return;
  const float4* sp = reinterpret_cast<const float4*>(s);
  float4 a = sp[2 * i], b = sp[2 * i + 1];
  u16x8 o;
  o[0] = f2bf_bits(a.x); o[1] = f2bf_bits(a.y); o[2] = f2bf_bits(a.z); o[3] = f2bf_bits(a.w);
  o[4] = f2bf_bits(b.x); o[5] = f2bf_bits(b.y); o[6] = f2bf_bits(b.z); o[7] = f2bf_bits(b.w);
  reinterpret_cast<u16x8*>(d)[i] = o;
}

// ---------------- GEMM: C[M,N] = A[M,K] * B[N,K]^T  (m97 structure) ----------------
// VT_MODE: write output transposed per-head: VT[b][h][d][t] (for attention V).
static __device__ __forceinline__ void store_c(float* p, float v)  { *p = v; }
static __device__ __forceinline__ void store_c(bf16_t* p, float v) { *p = f2bf(v); }

template <typename OutT, bool VT_MODE>
__global__ __launch_bounds__(256, 2) void gemm_bt(
    const bf16_t* __restrict__ A, const bf16_t* __restrict__ B, OutT* __restrict__ C) {
  __shared__ bf16_t As[128 * 32];
  __shared__ bf16_t Bs[128 * 32];
  const int tid = threadIdx.x;
  const int l = tid & 63, w = tid >> 6;
  const int wr = w >> 1, wc = w & 1;
  const int m0 = blockIdx.y * 128, n0 = blockIdx.x * 128;
  const int srow  = (l >> 2);
  const int skoff = (l & 3) * 8;

  f32x4 acc[4][4] = {};

  for (int k0 = 0; k0 < DM; k0 += 32) {
#pragma unroll
    for (int c = 0; c < 2; ++c) {
      const int chunk = w * 2 + c;
      const int row = chunk * 16 + srow;
      gll16(A + (size_t)(m0 + row) * DM + k0 + skoff, (char*)As + chunk * 1024);
      gll16(B + (size_t)(n0 + row) * DM + k0 + skoff, (char*)Bs + chunk * 1024);
    }
    __syncthreads();
    bf16x8 af[4], bfr[4];
    const bf16x8* Ap = reinterpret_cast<const bf16x8*>(As);
    const bf16x8* Bp = reinterpret_cast<const bf16x8*>(Bs);
#pragma unroll
    for (int m = 0; m < 4; ++m) af[m]  = Ap[(wr * 64 + m * 16 + (l & 15)) * 4 + (l >> 4)];
#pragma unroll
    for (int n = 0; n < 4; ++n) bfr[n] = Bp[(wc * 64 + n * 16 + (l & 15)) * 4 + (l >> 4)];
#pragma unroll
    for (int m = 0; m < 4; ++m)
#pragma unroll
      for (int n = 0; n < 4; ++n)
        acc[m][n] = __builtin_amdgcn_mfma_f32_16x16x32_bf16(af[m], bfr[n], acc[m][n], 0, 0, 0);
    __syncthreads();
  }

  if constexpr (VT_MODE) {
    // C row = b*TSEQ + t, col = h*HD + d  ->  VT[((b*NH+h)*HD + d)*TSEQ + t]
#pragma unroll
    for (int m = 0; m < 4; ++m) {
      const int row = m0 + wr * 64 + m * 16 + ((l >> 4) << 2);
      const int bb = row >> 11, tt = row & (TSEQ - 1);
#pragma unroll
      for (int n = 0; n < 4; ++n) {
        const int col = n0 + wc * 64 + n * 16 + (l & 15);
        const int hh = col >> 7, dd = col & (HD - 1);
        bf16x4 pk;
#pragma unroll
        for (int r = 0; r < 4; ++r) pk[r] = f2bf(acc[m][n][r]);
        *reinterpret_cast<bf16x4*>((bf16_t*)C + (((size_t)bb * NH + hh) * HD + dd) * TSEQ + tt) = pk;
      }
    }
  } else {
#pragma unroll
    for (int m = 0; m < 4; ++m) {
      const int row = m0 + wr * 64 + m * 16 + ((l >> 4) << 2);
#pragma unroll
      for (int n = 0; n < 4; ++n) {
        const int col = n0 + wc * 64 + n * 16 + (l & 15);
#pragma unroll
        for (int r = 0; r < 4; ++r)
          store_c(C + (size_t)(row + r) * DM + col, acc[m][n][r]);
      }
    }
  }
}

// ---------------- causal flash attention v3 ----------------
// grid: (T/128, B*H). Block: 512 thr = 8 waves, each wave 16 q-rows.
// 2-phase pipeline: STAGE(t+1) || COMPUTE(t); one barrier per iter.
// K  LDS: [64 kv][128 d], 256B rows, XOR-swizzled content (pre-swz global src).
// V^T LDS: [128 d][64 kv], 128B rows, same XOR swizzle -> PV mirrors QK.
__global__ __launch_bounds__(512, 4) void flash_attn(
    const bf16_t* __restrict__ Q, const bf16_t* __restrict__ Kx,
    const bf16_t* __restrict__ VT, bf16_t* __restrict__ O) {
  __shared__ bf16_t Ks[2][64 * 128];
  __shared__ bf16_t Vs[2][128 * 64];
  __shared__ bf16_t Ps[8][16 * 64];

  const int tid = threadIdx.x;
  const int l = tid & 63, w = tid >> 6;
  const int qb = (int)gridDim.x - 1 - (int)blockIdx.x;  // long blocks first
  const int bh = blockIdx.y;
  const int b = bh >> 4, h = bh & 15;
  const size_t base   = ((size_t)b * TSEQ) * DM + (size_t)h * HD;       // Q/K/O
  const size_t vtbase = ((size_t)b * NH + h) * HD * (size_t)TSEQ;       // V^T
  const int qbase = qb * 128;
  const int wrow0 = qbase + w * 16;
  const int nt = 2 * qb + 2;

  // Q fragments (A-layout: row=l&15, k=(l>>4)*8+j)
  bf16x8 qf[4];
  {
    const bf16_t* qp = Q + base + (size_t)(wrow0 + (l & 15)) * DM + (l >> 4) * 8;
#pragma unroll
    for (int ds = 0; ds < 4; ++ds)
      qf[ds] = *reinterpret_cast<const bf16x8*>(qp + ds * 32);
  }

  f32x4 acc[8] = {};
  float mrow[4] = {-1e30f, -1e30f, -1e30f, -1e30f};
  float lrow[4] = {0.f, 0.f, 0.f, 0.f};
  const float cc = 0.12752775f;  // (1/sqrt(128)) * log2(e)

  // ---- staging: per wave 2 K-chunks + 2 V^T-chunks of 1024B ----
  auto STAGE = [&](int t, int buf) {
#pragma unroll
    for (int c = 0; c < 2; ++c) {
      const int chunk = w * 2 + c;                   // 0..15
      const int krow = chunk * 4 + (l >> 4);
      const int u = l & 15;
      const int ug = (u & 8) | ((u ^ krow) & 7);
      gll16(Kx + base + (size_t)(t * 64 + krow) * DM + ug * 8,
            (char*)Ks[buf] + chunk * 1024);
    }
#pragma unroll
    for (int c = 0; c < 2; ++c) {
      const int ci = w * 2 + c;                      // 0..15
      const int d = ci * 8 + (l >> 3);               // d-row
      const int ug = (l & 7) ^ (l >> 3);             // (u ^ d) & 7
      gll16(VT + vtbase + (size_t)d * TSEQ + t * 64 + ug * 8,
            (char*)Vs[buf] + ci * 1024);
    }
  };

  STAGE(0, 0);
  __syncthreads();
  int cur = 0;

  for (int t = 0; t < nt; ++t) {
    if (t + 1 < nt) STAGE(t + 1, cur ^ 1);

    const bool active = (t * 64 <= wrow0 + 15);
    if (active) {
      // ---- S = Q K^T ----
      f32x4 s[4] = {};
      const char* Kb_ = (const char*)Ks[cur];
#pragma unroll
      for (int ct = 0; ct < 4; ++ct) {
        const int krow = ct * 16 + (l & 15);
#pragma unroll
        for (int ds = 0; ds < 4; ++ds) {
          const int u = ds * 4 + (l >> 4);
          const int uswz = (u & 8) | ((u ^ krow) & 7);
          const bf16x8 kf = *reinterpret_cast<const bf16x8*>(Kb_ + krow * 256 + uswz * 16);
          s[ct] = __builtin_amdgcn_mfma_f32_16x16x32_bf16(qf[ds], kf, s[ct], 0, 0, 0);
        }
      }

      float sv[4][4];
#pragma unroll
      for (int ct = 0; ct < 4; ++ct)
#pragma unroll
        for (int r = 0; r < 4; ++r)
          sv[ct][r] = s[ct][r] * cc;

      if (t * 64 + 63 > wrow0) {  // tile touches the diagonal for this wave
        const int rowg = wrow0 + ((l >> 4) << 2);
#pragma unroll
        for (int ct = 0; ct < 4; ++ct) {
          const int colg = t * 64 + ct * 16 + (l & 15);
#pragma unroll
          for (int r = 0; r < 4; ++r)
            if (colg > rowg + r) sv[ct][r] = -3.0e38f;
        }
      }

      // ---- wave-parallel online softmax (row = 16-lane group) ----
      float mt[4];
#pragma unroll
      for (int r = 0; r < 4; ++r)
        mt[r] = fmaxf(fmaxf(sv[0][r], sv[1][r]), fmaxf(sv[2][r], sv[3][r]));
#pragma unroll
      for (int r = 0; r < 4; ++r) {
        mt[r] = fmaxf(mt[r], __shfl_xor(mt[r], 1, 64));
        mt[r] = fmaxf(mt[r], __shfl_xor(mt[r], 2, 64));
        mt[r] = fmaxf(mt[r], __shfl_xor(mt[r], 4, 64));
        mt[r] = fmaxf(mt[r], __shfl_xor(mt[r], 8, 64));
      }
      // T13 defer-max: only rescale when the running max grew by > 8 (log2)
      bool needr = false;
#pragma unroll
      for (int r = 0; r < 4; ++r) needr |= (mt[r] > mrow[r] + 8.0f);
      if (__any(needr)) {
        float scl[4];
#pragma unroll
        for (int r = 0; r < 4; ++r) {
          const float mn = fmaxf(mrow[r], mt[r]);
          scl[r] = fast_exp2(mrow[r] - mn);
          mrow[r] = mn;
          lrow[r] *= scl[r];
        }
#pragma unroll
        for (int n = 0; n < 8; ++n)
#pragma unroll
          for (int r = 0; r < 4; ++r)
            acc[n][r] *= scl[r];
      }
      float rs[4] = {0.f, 0.f, 0.f, 0.f};
#pragma unroll
      for (int ct = 0; ct < 4; ++ct)
#pragma unroll
        for (int r = 0; r < 4; ++r) {
          const float p = fast_exp2(sv[ct][r] - mrow[r]);
          sv[ct][r] = p;
          rs[r] += p;
        }
#pragma unroll
      for (int r = 0; r < 4; ++r) {
        rs[r] += __shfl_xor(rs[r], 1, 64);
        rs[r] += __shfl_xor(rs[r], 2, 64);
        rs[r] += __shfl_xor(rs[r], 4, 64);
        rs[r] += __shfl_xor(rs[r], 8, 64);
        lrow[r] += rs[r];
      }

      // ---- P (D-layout) -> wave-private swizzled LDS ----
      bf16_t* Pw = Ps[w];
#pragma unroll
      for (int ct = 0; ct < 4; ++ct)
#pragma unroll
        for (int r = 0; r < 4; ++r) {
          const int prow = ((l >> 4) << 2) + r;
          const int pcol = ct * 16 + (l & 15);
          const int byteoff = (prow << 7) + ((pcol << 1) ^ ((prow & 7) << 4));
          *(bf16_t*)((char*)Pw + byteoff) = f2bf(sv[ct][r]);
        }

      // ---- O += P * V  (V^T rows read like K: swizzled ds_read_b128) ----
      const char* Vb_ = (const char*)Vs[cur];
#pragma unroll
      for (int ks = 0; ks < 2; ++ks) {
        const int prow = l & 15;
        const int pu = (ks * 4 + (l >> 4)) ^ (prow & 7);
        const bf16x8 pf = *reinterpret_cast<const bf16x8*>((const char*)Pw + prow * 128 + pu * 16);
#pragma unroll
        for (int n = 0; n < 8; ++n) {
          const int drow = n * 16 + (l & 15);
          const int u = ks * 4 + (l >> 4);
          const int uswz = u ^ (drow & 7);
          const bf16x8 vf = *reinterpret_cast<const bf16x8*>(Vb_ + drow * 128 + uswz * 16);
          acc[n] = __builtin_amdgcn_mfma_f32_16x16x32_bf16(pf, vf, acc[n], 0, 0, 0);
        }
      }
    }
    __syncthreads();
    cur ^= 1;
  }

  // ---- epilogue: normalize and store bf16 ----
#pragma unroll
  for (int r = 0; r < 4; ++r) {
    const float rl = fast_rcp(lrow[r]);
    const int row = wrow0 + ((l >> 4) << 2) + r;
    bf16_t* op = O + base + (size_t)row * DM + (l & 15);
#pragma unroll
    for (int n = 0; n < 8; ++n)
      op[n * 16] = f2bf(acc[n][r] * rl);
  }
}

// ---------------- launch ----------------
extern "C" void kernel_launch(void* const* d_in, const int* in_sizes, int n_in,
                              void* d_out, int out_size, void* d_ws, size_t ws_size,
                              hipStream_t stream) {
  (void)in_sizes; (void)n_in; (void)out_size; (void)ws_size;
  const float* x  = (const float*)d_in[0];
  const float* wq = (const float*)d_in[1];
  const float* wk = (const float*)d_in[2];
  const float* wv = (const float*)d_in[3];
  const float* wo = (const float*)d_in[4];
  float* out = (float*)d_out;

  const size_t nx = (size_t)MROWS * DM;  // 8388608
  const size_t nw = (size_t)DM * DM;     // 4194304
  bf16_t* xb  = (bf16_t*)d_ws;
  bf16_t* wqb = xb + nx;
  bf16_t* wkb = wqb + nw;
  bf16_t* wvb = wkb + nw;
  bf16_t* wob = wvb + nw;
  bf16_t* Qb  = wob + nw;
  bf16_t* Kb  = Qb + nx;
  bf16_t* Vtb = Kb + nx;   // V^T [B][H][d][t]
  bf16_t* Ab  = Vtb + nx;

  cvt_bf16<<<(int)(nx / 8 / 256), 256, 0, stream>>>(x, xb, (int)(nx / 8));
  cvt_bf16<<<(int)(nw / 8 / 256), 256, 0, stream>>>(wq, wqb, (int)(nw / 8));
  cvt_bf16<<<(int)(nw / 8 / 256), 256, 0, stream>>>(wk, wkb, (int)(nw / 8));
  cvt_bf16<<<(int)(nw / 8 / 256), 256, 0, stream>>>(wv, wvb, (int)(nw / 8));
  cvt_bf16<<<(int)(nw / 8 / 256), 256, 0, stream>>>(wo, wob, (int)(nw / 8));

  dim3 gg(DM / 128, MROWS / 128);  // (16, 32)
  gemm_bt<bf16_t, false><<<gg, 256, 0, stream>>>(xb, wqb, Qb);
  gemm_bt<bf16_t, false><<<gg, 256, 0, stream>>>(xb, wkb, Kb);
  gemm_bt<bf16_t, true ><<<gg, 256, 0, stream>>>(xb, wvb, Vtb);

  flash_attn<<<dim3(TSEQ / 128, BATCH * NH), 512, 0, stream>>>(Qb, Kb, Vtb, Ab);

  gemm_bt<float, false><<<gg, 256, 0, stream>>>(Ab, wob, out);
}

// Round 4
// 297.293 us; speedup vs baseline: 1.3834x; 1.1589x over previous
//
#include <hip/hip_runtime.h>

#define DM    2048
#define NH    16
#define HD    128
#define TSEQ  2048
#define BATCH 2
#define MROWS (BATCH * TSEQ)   // 4096

typedef __bf16 bf16_t;
typedef __bf16 bf16x8 __attribute__((ext_vector_type(8)));
typedef __bf16 bf16x4 __attribute__((ext_vector_type(4)));
typedef float  f32x4  __attribute__((ext_vector_type(4)));
typedef float  f32x16 __attribute__((ext_vector_type(16)));
typedef unsigned short u16x8 __attribute__((ext_vector_type(8)));
typedef unsigned int   u32;

static __device__ __forceinline__ unsigned short f2bf_bits(float f) {
  unsigned u = __builtin_bit_cast(unsigned, f);
  u += 0x7fffu + ((u >> 16) & 1u);            // round-to-nearest-even
  return (unsigned short)(u >> 16);
}
static __device__ __forceinline__ bf16_t f2bf(float f) {
  unsigned short h = f2bf_bits(f);
  return __builtin_bit_cast(bf16_t, h);
}

static __device__ __forceinline__ void gll16(const void* g, void* lds) {
  __builtin_amdgcn_global_load_lds(
      (const __attribute__((address_space(1))) unsigned int*)g,
      (__attribute__((address_space(3))) unsigned int*)lds, 16, 0, 0);
}

static __device__ __forceinline__ float fast_exp2(float x) {
#if __has_builtin(__builtin_amdgcn_exp2f)
  return __builtin_amdgcn_exp2f(x);
#else
  return exp2f(x);
#endif
}
static __device__ __forceinline__ float fast_rcp(float x) {
#if __has_builtin(__builtin_amdgcn_rcpf)
  return __builtin_amdgcn_rcpf(x);
#else
  return 1.0f / x;
#endif
}

// v_cvt_pk_bf16_f32: dst.lo16 = bf16(a), dst.hi16 = bf16(b)
static __device__ __forceinline__ u32 cvtpk(float a, float b) {
  u32 d;
  asm("v_cvt_pk_bf16_f32 %0, %1, %2" : "=v"(d) : "v"(a), "v"(b));
  return d;
}
// v_permlane32_swap_b32 a, b: a.hi32lanes <-> b.lo32lanes
static __device__ __forceinline__ void pl32swap(u32& a, u32& b) {
  asm volatile("v_permlane32_swap_b32 %0, %1" : "+v"(a), "+v"(b));
}

// ---------------- fp32 -> bf16 convert (vectorized, G13) ----------------
__global__ void cvt_bf16(const float* __restrict__ s, bf16_t* __restrict__ d, int n8) {
  int i = blockIdx.x * blockDim.x + threadIdx.x;
  if (i >= n8) return;
  const float4* sp = reinterpret_cast<const float4*>(s);
  float4 a = sp[2 * i], b = sp[2 * i + 1];
  u16x8 o;
  o[0] = f2bf_bits(a.x); o[1] = f2bf_bits(a.y); o[2] = f2bf_bits(a.z); o[3] = f2bf_bits(a.w);
  o[4] = f2bf_bits(b.x); o[5] = f2bf_bits(b.y); o[6] = f2bf_bits(b.z); o[7] = f2bf_bits(b.w);
  reinterpret_cast<u16x8*>(d)[i] = o;
}

// ---------------- GEMM: C[M,N] = A[M,K] * B[N,K]^T  (m97 structure) ----------------
static __device__ __forceinline__ void store_c(float* p, float v)  { *p = v; }
static __device__ __forceinline__ void store_c(bf16_t* p, float v) { *p = f2bf(v); }

template <typename OutT, bool VT_MODE>
__global__ __launch_bounds__(256, 2) void gemm_bt(
    const bf16_t* __restrict__ A, const bf16_t* __restrict__ B, OutT* __restrict__ C) {
  __shared__ bf16_t As[128 * 32];
  __shared__ bf16_t Bs[128 * 32];
  const int tid = threadIdx.x;
  const int l = tid & 63, w = tid >> 6;
  const int wr = w >> 1, wc = w & 1;
  const int m0 = blockIdx.y * 128, n0 = blockIdx.x * 128;
  const int srow  = (l >> 2);
  const int skoff = (l & 3) * 8;

  f32x4 acc[4][4] = {};

  for (int k0 = 0; k0 < DM; k0 += 32) {
#pragma unroll
    for (int c = 0; c < 2; ++c) {
      const int chunk = w * 2 + c;
      const int row = chunk * 16 + srow;
      gll16(A + (size_t)(m0 + row) * DM + k0 + skoff, (char*)As + chunk * 1024);
      gll16(B + (size_t)(n0 + row) * DM + k0 + skoff, (char*)Bs + chunk * 1024);
    }
    __syncthreads();
    bf16x8 af[4], bfr[4];
    const bf16x8* Ap = reinterpret_cast<const bf16x8*>(As);
    const bf16x8* Bp = reinterpret_cast<const bf16x8*>(Bs);
#pragma unroll
    for (int m = 0; m < 4; ++m) af[m]  = Ap[(wr * 64 + m * 16 + (l & 15)) * 4 + (l >> 4)];
#pragma unroll
    for (int n = 0; n < 4; ++n) bfr[n] = Bp[(wc * 64 + n * 16 + (l & 15)) * 4 + (l >> 4)];
#pragma unroll
    for (int m = 0; m < 4; ++m)
#pragma unroll
      for (int n = 0; n < 4; ++n)
        acc[m][n] = __builtin_amdgcn_mfma_f32_16x16x32_bf16(af[m], bfr[n], acc[m][n], 0, 0, 0);
    __syncthreads();
  }

  if constexpr (VT_MODE) {
    // C row = b*TSEQ + t, col = h*HD + d  ->  VT[((b*NH+h)*HD + d)*TSEQ + t]
#pragma unroll
    for (int m = 0; m < 4; ++m) {
      const int row = m0 + wr * 64 + m * 16 + ((l >> 4) << 2);
      const int bb = row >> 11, tt = row & (TSEQ - 1);
#pragma unroll
      for (int n = 0; n < 4; ++n) {
        const int col = n0 + wc * 64 + n * 16 + (l & 15);
        const int hh = col >> 7, dd = col & (HD - 1);
        bf16x4 pk;
#pragma unroll
        for (int r = 0; r < 4; ++r) pk[r] = f2bf(acc[m][n][r]);
        *reinterpret_cast<bf16x4*>((bf16_t*)C + (((size_t)bb * NH + hh) * HD + dd) * TSEQ + tt) = pk;
      }
    }
  } else {
#pragma unroll
    for (int m = 0; m < 4; ++m) {
      const int row = m0 + wr * 64 + m * 16 + ((l >> 4) << 2);
#pragma unroll
      for (int n = 0; n < 4; ++n) {
        const int col = n0 + wc * 64 + n * 16 + (l & 15);
#pragma unroll
        for (int r = 0; r < 4; ++r)
          store_c(C + (size_t)(row + r) * DM + col, acc[m][n][r]);
      }
    }
  }
}

// ---------------- causal flash attention v4: swapped-QK 32x32, in-reg softmax ----
// grid: (T/128, B*H). Block: 256 thr = 4 waves, each wave 32 q-rows.
// S^T = mfma_32x32x16(K, Q): lane owns q-row (l&31); kv per reg r: crow(r,hi).
// P stays in registers (cvt_pk + permlane32_swap -> PV A-frags). KVBLK=64, dbuf.
__global__ __launch_bounds__(256, 2) void flash_attn(
    const bf16_t* __restrict__ Q, const bf16_t* __restrict__ Kx,
    const bf16_t* __restrict__ VT, bf16_t* __restrict__ O) {
  __shared__ bf16_t Ks[2][64 * 128];   // [kv][d], 256B rows, XOR-swizzled content
  __shared__ bf16_t Vs[2][128 * 64];   // [d][kv], 128B rows, XOR-swizzled content
  __shared__ float  Ms[4][32];         // per-wave scl/lrow redistribute buffer

  const int tid = threadIdx.x;
  const int l = tid & 63, w = tid >> 6;
  const int hi = l >> 5, ln31 = l & 31;
  const int qb = (int)gridDim.x - 1 - (int)blockIdx.x;  // long blocks first
  const int bh = blockIdx.y;
  const int b = bh >> 4, h = bh & 15;
  const size_t base   = ((size_t)b * TSEQ) * DM + (size_t)h * HD;   // Q/K/O
  const size_t vtbase = ((size_t)b * NH + h) * HD * (size_t)TSEQ;   // V^T
  const int qbase = qb * 128;
  const int wq0 = qbase + w * 32;
  const int nt = 2 * qb + 2;

  // Q as B-operand: lane holds col q = ln31, k(d) = m*16 + hi*8 + j
  bf16x8 qf[8];
  {
    const bf16_t* qp = Q + base + (size_t)(wq0 + ln31) * DM + hi * 8;
#pragma unroll
    for (int m = 0; m < 8; ++m)
      qf[m] = *reinterpret_cast<const bf16x8*>(qp + m * 16);
  }

  f32x16 acc[4] = {};   // O: row q=crow(r,hi), col d = n*32 + ln31
  float mrow = -1e30f, lrow = 0.f;
  const float cc = 0.12752775f;  // (1/sqrt(128)) * log2(e)

  auto STAGE = [&](int t, int buf) {
#pragma unroll
    for (int c = 0; c < 4; ++c) {
      const int chunk = w * 4 + c;                   // 0..15
      const int krow = chunk * 4 + (l >> 4);
      const int u = l & 15;
      const int ug = (u & 8) | ((u ^ krow) & 7);
      gll16(Kx + base + (size_t)(t * 64 + krow) * DM + ug * 8,
            (char*)Ks[buf] + chunk * 1024);
    }
#pragma unroll
    for (int c = 0; c < 4; ++c) {
      const int ci = w * 4 + c;                      // 0..15
      const int d = ci * 8 + (l >> 3);
      const int ug = (l & 7) ^ (l >> 3);
      gll16(VT + vtbase + (size_t)d * TSEQ + t * 64 + ug * 8,
            (char*)Vs[buf] + ci * 1024);
    }
  };

  STAGE(0, 0);
  __syncthreads();
  int cur = 0;

  for (int t = 0; t < nt; ++t) {
    if (t + 1 < nt) STAGE(t + 1, cur ^ 1);

    const bool active = (t * 64 <= wq0 + 31);
    if (active) {
      // ---- S^T = K Q^T : 2 kv-subtiles of 32 ----
      f32x16 s[2] = {};
      const char* Kb_ = (const char*)Ks[cur];
#pragma unroll
      for (int si = 0; si < 2; ++si) {
        const int kvr = si * 32 + ln31;
#pragma unroll
        for (int m = 0; m < 8; ++m) {
          const int u = 2 * m + hi;
          const int uswz = (u & 8) | ((u ^ kvr) & 7);
          const bf16x8 kf = *reinterpret_cast<const bf16x8*>(Kb_ + kvr * 256 + uswz * 16);
          s[si] = __builtin_amdgcn_mfma_f32_32x32x16_bf16(kf, qf[m], s[si], 0, 0, 0);
        }
      }

      // ---- scale + causal mask (per-lane: q = ln31, kv = crow(r,hi)) ----
      float sv[32];
      const int qg = wq0 + ln31;
#pragma unroll
      for (int si = 0; si < 2; ++si)
#pragma unroll
        for (int r = 0; r < 16; ++r)
          sv[si * 16 + r] = s[si][r] * cc;
      if (t * 64 + 63 > wq0) {
#pragma unroll
        for (int si = 0; si < 2; ++si)
#pragma unroll
          for (int r = 0; r < 16; ++r) {
            const int kvg = t * 64 + si * 32 + (r & 3) + 8 * (r >> 2) + 4 * hi;
            if (kvg > qg) sv[si * 16 + r] = -3.0e38f;
          }
      }

      // ---- in-register row max (own 32) + cross-half combine ----
      float mt = sv[0];
#pragma unroll
      for (int r = 1; r < 32; ++r) mt = fmaxf(mt, sv[r]);
      mt = fmaxf(mt, __shfl_xor(mt, 32, 64));

      // T13 defer-max
      if (__any(mt > mrow + 8.0f)) {
        const float mn = fmaxf(mrow, mt);
        const float scl = fast_exp2(mrow - mn);
        mrow = mn;
        lrow *= scl;
        if (hi == 0) Ms[w][ln31] = scl;
        float sclg[16];
#pragma unroll
        for (int r = 0; r < 16; ++r)
          sclg[r] = Ms[w][(r & 3) + 8 * (r >> 2) + 4 * hi];
#pragma unroll
        for (int n = 0; n < 4; ++n)
#pragma unroll
          for (int r = 0; r < 16; ++r)
            acc[n][r] *= sclg[r];
      }

      // ---- P = exp2(S - m), row sum ----
      float rs = 0.f;
#pragma unroll
      for (int r = 0; r < 32; ++r) {
        const float p = fast_exp2(sv[r] - mrow);
        sv[r] = p;
        rs += p;
      }
      rs += __shfl_xor(rs, 32, 64);
      lrow += rs;

      // ---- cvt_pk + permlane32_swap: build PV A-frags (kv-slot ks=0..3) ----
      u32 frag[4][4];
#pragma unroll
      for (int si = 0; si < 2; ++si) {
#pragma unroll
        for (int half = 0; half < 2; ++half) {
          const float* p = &sv[si * 16 + half * 8];
          u32 a1 = cvtpk(p[0], p[1]);
          u32 b1 = cvtpk(p[4], p[5]);
          pl32swap(a1, b1);
          u32 a2 = cvtpk(p[2], p[3]);
          u32 b2 = cvtpk(p[6], p[7]);
          pl32swap(a2, b2);
          frag[si * 2 + half][0] = a1;
          frag[si * 2 + half][1] = a2;
          frag[si * 2 + half][2] = b1;
          frag[si * 2 + half][3] = b2;
        }
      }

      // ---- O += P V : 4 kv-slots x 4 d-tiles ----
      const char* Vb_ = (const char*)Vs[cur];
#pragma unroll
      for (int ks = 0; ks < 4; ++ks) {
        const bf16x8 pf = __builtin_bit_cast(bf16x8, *reinterpret_cast<u32(*)[4]>(frag[ks]));
#pragma unroll
        for (int n = 0; n < 4; ++n) {
          const int d = n * 32 + ln31;
          const int u = ks * 2 + hi;
          const int uswz = u ^ (d & 7);
          const bf16x8 vf = *reinterpret_cast<const bf16x8*>(Vb_ + d * 128 + uswz * 16);
          acc[n] = __builtin_amdgcn_mfma_f32_32x32x16_bf16(pf, vf, acc[n], 0, 0, 0);
        }
      }
    }
    __syncthreads();
    cur ^= 1;
  }

  // ---- epilogue: redistribute lrow across crow layout, normalize, store ----
  if (hi == 0) Ms[w][ln31] = lrow;
  __syncthreads();
  float rl[16];
#pragma unroll
  for (int r = 0; r < 16; ++r)
    rl[r] = fast_rcp(Ms[w][(r & 3) + 8 * (r >> 2) + 4 * hi]);
#pragma unroll
  for (int r = 0; r < 16; ++r) {
    const int q = wq0 + (r & 3) + 8 * (r >> 2) + 4 * hi;
    bf16_t* op = O + base + (size_t)q * DM + ln31;
#pragma unroll
    for (int n = 0; n < 4; ++n)
      op[n * 32] = f2bf(acc[n][r] * rl[r]);
  }
}

// ---------------- launch ----------------
extern "C" void kernel_launch(void* const* d_in, const int* in_sizes, int n_in,
                              void* d_out, int out_size, void* d_ws, size_t ws_size,
                              hipStream_t stream) {
  (void)in_sizes; (void)n_in; (void)out_size; (void)ws_size;
  const float* x  = (const float*)d_in[0];
  const float* wq = (const float*)d_in[1];
  const float* wk = (const float*)d_in[2];
  const float* wv = (const float*)d_in[3];
  const float* wo = (const float*)d_in[4];
  float* out = (float*)d_out;

  const size_t nx = (size_t)MROWS * DM;  // 8388608
  const size_t nw = (size_t)DM * DM;     // 4194304
  bf16_t* xb  = (bf16_t*)d_ws;
  bf16_t* wqb = xb + nx;
  bf16_t* wkb = wqb + nw;
  bf16_t* wvb = wkb + nw;
  bf16_t* wob = wvb + nw;
  bf16_t* Qb  = wob + nw;
  bf16_t* Kb  = Qb + nx;
  bf16_t* Vtb = Kb + nx;   // V^T [B][H][d][t]
  bf16_t* Ab  = Vtb + nx;

  cvt_bf16<<<(int)(nx / 8 / 256), 256, 0, stream>>>(x, xb, (int)(nx / 8));
  cvt_bf16<<<(int)(nw / 8 / 256), 256, 0, stream>>>(wq, wqb, (int)(nw / 8));
  cvt_bf16<<<(int)(nw / 8 / 256), 256, 0, stream>>>(wk, wkb, (int)(nw / 8));
  cvt_bf16<<<(int)(nw / 8 / 256), 256, 0, stream>>>(wv, wvb, (int)(nw / 8));
  cvt_bf16<<<(int)(nw / 8 / 256), 256, 0, stream>>>(wo, wob, (int)(nw / 8));

  dim3 gg(DM / 128, MROWS / 128);  // (16, 32)
  gemm_bt<bf16_t, false><<<gg, 256, 0, stream>>>(xb, wqb, Qb);
  gemm_bt<bf16_t, false><<<gg, 256, 0, stream>>>(xb, wkb, Kb);
  gemm_bt<bf16_t, true ><<<gg, 256, 0, stream>>>(xb, wvb, Vtb);

  flash_attn<<<dim3(TSEQ / 128, BATCH * NH), 256, 0, stream>>>(Qb, Kb, Vtb, Ab);

  gemm_bt<float, false><<<gg, 256, 0, stream>>>(Ab, wob, out);
}